// Round 1
// baseline (1175.202 us; speedup 1.0000x reference)
//
#include <hip/hip_runtime.h>

#define TPB 256

// ---------------- degree / norm ----------------

__global__ __launch_bounds__(TPB) void k_deg_init(float* __restrict__ deg, int N) {
    int i = blockIdx.x * TPB + threadIdx.x;
    if (i < N) deg[i] = 1.0f;   // self-loop
}

__global__ __launch_bounds__(TPB) void k_deg_count(const int* __restrict__ dst,
                                                   float* __restrict__ deg, int E) {
    int e = blockIdx.x * TPB + threadIdx.x;
    if (e < E) atomicAdd(&deg[dst[e]], 1.0f);
}

__global__ __launch_bounds__(TPB) void k_dinv(float* __restrict__ deg, int N) {
    int i = blockIdx.x * TPB + threadIdx.x;
    if (i < N) deg[i] = rsqrtf(deg[i]);   // deg >= 1 always (self-loops)
}

// ---------------- GEMM1: H[N,64] = X[N,128] @ W[128,64] ----------------
// 64-row tile; X tile is a contiguous 32KB block (row-major), W fully in LDS.
// Xs row stride 132 floats (pad +4, float4-aligned): bank = (4r+k)%32 -> worst
// 2-way conflict (free). W reads are 4-address broadcasts (<=2-way).

__global__ __launch_bounds__(TPB) void k_gemm1(const float* __restrict__ X,
                                               const float* __restrict__ W,
                                               float* __restrict__ H, int N) {
    __shared__ float Xs[64 * 132];
    __shared__ float Ws[128 * 64];
    int t = threadIdx.x;
    int row0 = blockIdx.x * 64;

    const float4* W4 = (const float4*)W;
    float4* Ws4 = (float4*)Ws;
#pragma unroll
    for (int i = 0; i < 8; i++) Ws4[t + i * 256] = W4[t + i * 256];

    int rows = N - row0; if (rows > 64) rows = 64;
    const float4* X4 = (const float4*)(X + (size_t)row0 * 128);
    float4* Xs4 = (float4*)Xs;
    for (int i = t; i < rows * 32; i += TPB) {
        int rr = i >> 5, kk = i & 31;
        Xs4[rr * 33 + kk] = X4[i];
    }
    __syncthreads();

    int r = t >> 2;
    int c0 = (t & 3) * 16;
    float acc[16];
#pragma unroll
    for (int j = 0; j < 16; j++) acc[j] = 0.0f;
    const float* xrow = Xs + r * 132;
#pragma unroll 2
    for (int k = 0; k < 128; k++) {
        float xv = xrow[k];
        const float* wr = Ws + k * 64 + c0;
#pragma unroll
        for (int j = 0; j < 16; j++) acc[j] += xv * wr[j];
    }
    if (row0 + r < N) {
        float* o = H + (size_t)(row0 + r) * 64 + c0;
#pragma unroll
        for (int j = 0; j < 16; j++) o[j] = acc[j];
    }
}

// ---------------- GEMM2: H[N,32] = relu(Xin[N,64]) @ W[64,32] ----------------

__global__ __launch_bounds__(TPB) void k_gemm2(const float* __restrict__ Xin,
                                               const float* __restrict__ W,
                                               float* __restrict__ H, int N) {
    __shared__ float Xs[64 * 68];
    __shared__ float Ws[64 * 32];
    int t = threadIdx.x;
    int row0 = blockIdx.x * 64;

    const float4* W4 = (const float4*)W;
    float4* Ws4 = (float4*)Ws;
#pragma unroll
    for (int i = 0; i < 2; i++) Ws4[t + i * 256] = W4[t + i * 256];

    int rows = N - row0; if (rows > 64) rows = 64;
    const float4* X4 = (const float4*)(Xin + (size_t)row0 * 64);
    float4* Xs4 = (float4*)Xs;
    for (int i = t; i < rows * 16; i += TPB) {
        int rr = i >> 4, kk = i & 15;
        float4 v = X4[i];
        v.x = fmaxf(v.x, 0.0f); v.y = fmaxf(v.y, 0.0f);
        v.z = fmaxf(v.z, 0.0f); v.w = fmaxf(v.w, 0.0f);
        Xs4[rr * 17 + kk] = v;
    }
    __syncthreads();

    int r = t >> 2;
    int c0 = (t & 3) * 8;
    float acc[8];
#pragma unroll
    for (int j = 0; j < 8; j++) acc[j] = 0.0f;
    const float* xrow = Xs + r * 68;
#pragma unroll 4
    for (int k = 0; k < 64; k++) {
        float xv = xrow[k];
        const float* wr = Ws + k * 32 + c0;
#pragma unroll
        for (int j = 0; j < 8; j++) acc[j] += xv * wr[j];
    }
    if (row0 + r < N) {
        float* o = H + (size_t)(row0 + r) * 32 + c0;
#pragma unroll
        for (int j = 0; j < 8; j++) o[j] = acc[j];
    }
}

// ------------- out init: out[n][:] = h[n][:] * dinv[n]^2 + b  (self-loop + bias) -------------
// Q4 = number of float4 chunks per row (16 for F=64, 8 for F=32)

template <int Q4>
__global__ __launch_bounds__(TPB) void k_init_out(const float* __restrict__ H,
                                                  const float* __restrict__ dinv,
                                                  const float* __restrict__ b,
                                                  float* __restrict__ out, int N) {
    int tid = blockIdx.x * TPB + threadIdx.x;
    if (tid >= N * Q4) return;
    int n = tid / Q4, q = tid % Q4;
    float w = dinv[n]; w *= w;
    float4 v = ((const float4*)H)[tid];
    float4 bb = ((const float4*)b)[q];
    float4 o = { v.x * w + bb.x, v.y * w + bb.y, v.z * w + bb.z, v.w * w + bb.w };
    ((float4*)out)[tid] = o;
}

// ------------- edge scatter: out[dst] += h[src] * dinv[src]*dinv[dst] -------------
// 16 (or 8) threads per edge, one float4 each -> coalesced gather of the h row.

template <int Q4>
__global__ __launch_bounds__(TPB) void k_scatter(const int* __restrict__ src,
                                                 const int* __restrict__ dst,
                                                 const float* __restrict__ dinv,
                                                 const float* __restrict__ H,
                                                 float* __restrict__ out, int E) {
    int tid = blockIdx.x * TPB + threadIdx.x;
    if (tid >= E * Q4) return;
    int e = tid / Q4;
    int q = tid % Q4;
    int s = src[e], d = dst[e];
    float w = dinv[s] * dinv[d];
    float4 v = ((const float4*)H)[s * Q4 + q];
    float* o = out + (size_t)d * (Q4 * 4) + q * 4;
    atomicAdd(o + 0, v.x * w);
    atomicAdd(o + 1, v.y * w);
    atomicAdd(o + 2, v.z * w);
    atomicAdd(o + 3, v.w * w);
}

__global__ __launch_bounds__(TPB) void k_relu(float* __restrict__ out, int n4) {
    int i = blockIdx.x * TPB + threadIdx.x;
    if (i < n4) {
        float4 v = ((float4*)out)[i];
        v.x = fmaxf(v.x, 0.0f); v.y = fmaxf(v.y, 0.0f);
        v.z = fmaxf(v.z, 0.0f); v.w = fmaxf(v.w, 0.0f);
        ((float4*)out)[i] = v;
    }
}

static inline int cdiv(int a, int b) { return (a + b - 1) / b; }

extern "C" void kernel_launch(void* const* d_in, const int* in_sizes, int n_in,
                              void* d_out, int out_size, void* d_ws, size_t ws_size,
                              hipStream_t stream) {
    const float* x  = (const float*)d_in[0];
    const int*   ei = (const int*)d_in[1];
    const float* W1 = (const float*)d_in[2];
    const float* b1 = (const float*)d_in[3];
    const float* W2 = (const float*)d_in[4];
    const float* b2 = (const float*)d_in[5];
    float* out = (float*)d_out;

    int N = in_sizes[0] / 128;
    int E = in_sizes[1] / 2;
    const int* src = ei;
    const int* dst = ei + E;

    char* ws = (char*)d_ws;
    size_t o1 = ((size_t)N * 4 + 255) & ~(size_t)255;
    float* dinv = (float*)ws;                 // N floats (deg -> dinv in place)
    float* h1   = (float*)(ws + o1);          // N*64
    float* out1 = h1 + (size_t)N * 64;        // N*64 (pre-relu layer-1 output)
    float* h2   = out1 + (size_t)N * 64;      // N*32

    dim3 b(TPB);

    k_deg_init <<<cdiv(N, TPB), b, 0, stream>>>(dinv, N);
    k_deg_count<<<cdiv(E, TPB), b, 0, stream>>>(dst, dinv, E);
    k_dinv     <<<cdiv(N, TPB), b, 0, stream>>>(dinv, N);

    // layer 1
    k_gemm1        <<<cdiv(N, 64), b, 0, stream>>>(x, W1, h1, N);
    k_init_out<16> <<<cdiv(N * 16, TPB), b, 0, stream>>>(h1, dinv, b1, out1, N);
    k_scatter<16>  <<<cdiv(E * 16, TPB), b, 0, stream>>>(src, dst, dinv, h1, out1, E);

    // layer 2 (relu of out1 fused into gemm2 load)
    k_gemm2        <<<cdiv(N, 64), b, 0, stream>>>(out1, W2, h2, N);
    k_init_out<8>  <<<cdiv(N * 8, TPB), b, 0, stream>>>(h2, dinv, b2, out, N);
    k_scatter<8>   <<<cdiv(E * 8, TPB), b, 0, stream>>>(src, dst, dinv, h2, out, E);
    k_relu         <<<cdiv(N * 8, TPB), b, 0, stream>>>(out, N * 8);
}

// Round 2
// 296.242 us; speedup vs baseline: 3.9670x; 3.9670x over previous
//
#include <hip/hip_runtime.h>

#define TPB 256
#define SCAN_CHUNK 1024   // elements per scan block (256 thr x 4)

// ---------------- CSR build ----------------

__global__ __launch_bounds__(TPB) void k_zero(int* __restrict__ cnt, int N) {
    int i = blockIdx.x * TPB + threadIdx.x;
    if (i < N) cnt[i] = 0;
}

__global__ __launch_bounds__(TPB) void k_hist(const int* __restrict__ dst,
                                              int* __restrict__ cnt, int E) {
    int e = blockIdx.x * TPB + threadIdx.x;
    if (e < E) atomicAdd(&cnt[dst[e]], 1);
}

__global__ __launch_bounds__(TPB) void k_dinv(const int* __restrict__ cnt,
                                              float* __restrict__ dinv, int N) {
    int i = blockIdx.x * TPB + threadIdx.x;
    if (i < N) dinv[i] = rsqrtf((float)(cnt[i] + 1));   // +1 self-loop, deg>=1
}

// scan pass A: per-block sums of SCAN_CHUNK counts
__global__ __launch_bounds__(TPB) void k_scan_a(const int* __restrict__ cnt,
                                                int* __restrict__ bsum, int N) {
    __shared__ int sh[TPB];
    int t = threadIdx.x;
    int base = blockIdx.x * SCAN_CHUNK + t * 4;
    int s = 0;
#pragma unroll
    for (int j = 0; j < 4; j++) { int idx = base + j; if (idx < N) s += cnt[idx]; }
    sh[t] = s; __syncthreads();
    for (int off = TPB / 2; off > 0; off >>= 1) {
        if (t < off) sh[t] += sh[t + off];
        __syncthreads();
    }
    if (t == 0) bsum[blockIdx.x] = sh[0];
}

// scan pass B: serial exclusive scan of block sums (nblocks ~ 49)
__global__ void k_scan_b(const int* __restrict__ bsum, int* __restrict__ boff, int nb) {
    if (threadIdx.x == 0 && blockIdx.x == 0) {
        int run = 0;
        for (int i = 0; i < nb; i++) { boff[i] = run; run += bsum[i]; }
    }
}

// scan pass C: full exclusive scan -> rowptr, duplicate into cursor
__global__ __launch_bounds__(TPB) void k_scan_c(const int* __restrict__ cnt,
                                                const int* __restrict__ boff,
                                                int* __restrict__ rowptr,
                                                int* __restrict__ cursor, int N, int E) {
    __shared__ int sh[TPB];
    int t = threadIdx.x;
    int base = blockIdx.x * SCAN_CHUNK + t * 4;
    int v[4];
#pragma unroll
    for (int j = 0; j < 4; j++) { int idx = base + j; v[j] = (idx < N) ? cnt[idx] : 0; }
    int tsum = v[0] + v[1] + v[2] + v[3];
    sh[t] = tsum; __syncthreads();
    for (int off = 1; off < TPB; off <<= 1) {
        int x = (t >= off) ? sh[t - off] : 0;
        __syncthreads();
        sh[t] += x;
        __syncthreads();
    }
    int excl = sh[t] - tsum + boff[blockIdx.x];
#pragma unroll
    for (int j = 0; j < 4; j++) {
        int idx = base + j;
        if (idx < N) { rowptr[idx] = excl; cursor[idx] = excl; }
        excl += v[j];
    }
    if (blockIdx.x == 0 && t == 0) rowptr[N] = E;
}

// fill: slot edges into CSR, precompute edge weight dinv[s]*dinv[d]
__global__ __launch_bounds__(TPB) void k_fill(const int* __restrict__ src,
                                              const int* __restrict__ dst,
                                              const float* __restrict__ dinv,
                                              int* __restrict__ cursor,
                                              int* __restrict__ srcs,
                                              float* __restrict__ wts, int E) {
    int e = blockIdx.x * TPB + threadIdx.x;
    if (e >= E) return;
    int s = src[e], d = dst[e];
    int pos = atomicAdd(&cursor[d], 1);
    srcs[pos] = s;
    wts[pos]  = dinv[s] * dinv[d];
}

// ---------------- GEMM1: H[N,64] = X[N,128] @ W[128,64] ----------------

__global__ __launch_bounds__(TPB) void k_gemm1(const float* __restrict__ X,
                                               const float* __restrict__ W,
                                               float* __restrict__ H, int N) {
    __shared__ float Xs[64 * 132];
    __shared__ float Ws[128 * 64];
    int t = threadIdx.x;
    int row0 = blockIdx.x * 64;

    const float4* W4 = (const float4*)W;
    float4* Ws4 = (float4*)Ws;
#pragma unroll
    for (int i = 0; i < 8; i++) Ws4[t + i * 256] = W4[t + i * 256];

    int rows = N - row0; if (rows > 64) rows = 64;
    const float4* X4 = (const float4*)(X + (size_t)row0 * 128);
    float4* Xs4 = (float4*)Xs;
    for (int i = t; i < rows * 32; i += TPB) {
        int rr = i >> 5, kk = i & 31;
        Xs4[rr * 33 + kk] = X4[i];
    }
    __syncthreads();

    int r = t >> 2;
    int c0 = (t & 3) * 16;
    float acc[16];
#pragma unroll
    for (int j = 0; j < 16; j++) acc[j] = 0.0f;
    const float* xrow = Xs + r * 132;
#pragma unroll 2
    for (int k = 0; k < 128; k++) {
        float xv = xrow[k];
        const float* wr = Ws + k * 64 + c0;
#pragma unroll
        for (int j = 0; j < 16; j++) acc[j] += xv * wr[j];
    }
    if (row0 + r < N) {
        float* o = H + (size_t)(row0 + r) * 64 + c0;
#pragma unroll
        for (int j = 0; j < 16; j++) o[j] = acc[j];
    }
}

// ---------------- GEMM2: H[N,32] = Xin[N,64] @ W[64,32] (Xin already relu'd) ----------------

__global__ __launch_bounds__(TPB) void k_gemm2(const float* __restrict__ Xin,
                                               const float* __restrict__ W,
                                               float* __restrict__ H, int N) {
    __shared__ float Xs[64 * 68];
    __shared__ float Ws[64 * 32];
    int t = threadIdx.x;
    int row0 = blockIdx.x * 64;

    const float4* W4 = (const float4*)W;
    float4* Ws4 = (float4*)Ws;
#pragma unroll
    for (int i = 0; i < 2; i++) Ws4[t + i * 256] = W4[t + i * 256];

    int rows = N - row0; if (rows > 64) rows = 64;
    const float4* X4 = (const float4*)(Xin + (size_t)row0 * 64);
    float4* Xs4 = (float4*)Xs;
    for (int i = t; i < rows * 16; i += TPB) {
        int rr = i >> 4, kk = i & 15;
        Xs4[rr * 17 + kk] = X4[i];
    }
    __syncthreads();

    int r = t >> 2;
    int c0 = (t & 3) * 8;
    float acc[8];
#pragma unroll
    for (int j = 0; j < 8; j++) acc[j] = 0.0f;
    const float* xrow = Xs + r * 68;
#pragma unroll 4
    for (int k = 0; k < 64; k++) {
        float xv = xrow[k];
        const float* wr = Ws + k * 32 + c0;
#pragma unroll
        for (int j = 0; j < 8; j++) acc[j] += xv * wr[j];
    }
    if (row0 + r < N) {
        float* o = H + (size_t)(row0 + r) * 32 + c0;
#pragma unroll
        for (int j = 0; j < 8; j++) o[j] = acc[j];
    }
}

// ---------------- gather: out[n][c] = relu( sum_{e in CSR[n]} H[srcs[e]][c]*wts[e]
//                                           + H[n][c]*dinv[n]^2 + b[c] ) ----------------
// F lanes per node: srcs/wts loads are same-address broadcasts within the node's
// lane group; H row reads are coalesced F*4-byte transactions.

template <int F>
__global__ __launch_bounds__(TPB) void k_gather(const int* __restrict__ rowptr,
                                                const int* __restrict__ srcs,
                                                const float* __restrict__ wts,
                                                const float* __restrict__ H,
                                                const float* __restrict__ dinv,
                                                const float* __restrict__ bias,
                                                float* __restrict__ out, int N) {
    int t = threadIdx.x;
    int node = blockIdx.x * (TPB / F) + t / F;
    int c = t % F;
    if (node >= N) return;
    float w0 = dinv[node];
    float acc = H[(size_t)node * F + c] * (w0 * w0) + bias[c];
    int i = rowptr[node], end = rowptr[node + 1];
    for (; i + 1 < end; i += 2) {
        int s0 = srcs[i], s1 = srcs[i + 1];
        float wa = wts[i], wb = wts[i + 1];
        float ha = H[(size_t)s0 * F + c];
        float hb = H[(size_t)s1 * F + c];
        acc = fmaf(ha, wa, acc);
        acc = fmaf(hb, wb, acc);
    }
    if (i < end) acc = fmaf(H[(size_t)srcs[i] * F + c], wts[i], acc);
    out[(size_t)node * F + c] = fmaxf(acc, 0.0f);
}

static inline int cdiv(int a, int b) { return (a + b - 1) / b; }
static inline char* alignup(char* p) { return (char*)(((uintptr_t)p + 255) & ~(uintptr_t)255); }

extern "C" void kernel_launch(void* const* d_in, const int* in_sizes, int n_in,
                              void* d_out, int out_size, void* d_ws, size_t ws_size,
                              hipStream_t stream) {
    const float* x  = (const float*)d_in[0];
    const int*   ei = (const int*)d_in[1];
    const float* W1 = (const float*)d_in[2];
    const float* b1 = (const float*)d_in[3];
    const float* W2 = (const float*)d_in[4];
    const float* b2 = (const float*)d_in[5];
    float* out = (float*)d_out;

    int N = in_sizes[0] / 128;
    int E = in_sizes[1] / 2;
    const int* src = ei;
    const int* dst = ei + E;

    char* p = (char*)d_ws;
    float* dinv  = (float*)p;            p = alignup(p + sizeof(float) * N);
    int* cnt     = (int*)p;              p = alignup(p + sizeof(int) * N);
    int* rowptr  = (int*)p;              p = alignup(p + sizeof(int) * (N + 1));
    int* cursor  = (int*)p;              p = alignup(p + sizeof(int) * N);
    int* bsum    = (int*)p;              p = alignup(p + sizeof(int) * 256);
    int* boff    = (int*)p;              p = alignup(p + sizeof(int) * 256);
    int* srcs    = (int*)p;              p = alignup(p + sizeof(int) * E);
    float* wts   = (float*)p;            p = alignup(p + sizeof(float) * E);
    float* h1    = (float*)p;            p = alignup(p + sizeof(float) * (size_t)N * 64);
    float* out1  = (float*)p;            p = alignup(p + sizeof(float) * (size_t)N * 64);
    float* h2    = (float*)p;            p = alignup(p + sizeof(float) * (size_t)N * 32);

    dim3 b(TPB);
    int nscan = cdiv(N, SCAN_CHUNK);

    // ---- CSR build (also produces dinv) ----
    k_zero  <<<cdiv(N, TPB), b, 0, stream>>>(cnt, N);
    k_hist  <<<cdiv(E, TPB), b, 0, stream>>>(dst, cnt, E);
    k_dinv  <<<cdiv(N, TPB), b, 0, stream>>>(cnt, dinv, N);
    k_scan_a<<<nscan, b, 0, stream>>>(cnt, bsum, N);
    k_scan_b<<<1, 64, 0, stream>>>(bsum, boff, nscan);
    k_scan_c<<<nscan, b, 0, stream>>>(cnt, boff, rowptr, cursor, N, E);
    k_fill  <<<cdiv(E, TPB), b, 0, stream>>>(src, dst, dinv, cursor, srcs, wts, E);

    // ---- layer 1 ----
    k_gemm1      <<<cdiv(N, 64), b, 0, stream>>>(x, W1, h1, N);
    k_gather<64> <<<cdiv(N, TPB / 64), b, 0, stream>>>(rowptr, srcs, wts, h1, dinv, b1, out1, N);

    // ---- layer 2 ----
    k_gemm2      <<<cdiv(N, 64), b, 0, stream>>>(out1, W2, h2, N);
    k_gather<32> <<<cdiv(N, TPB / 32), b, 0, stream>>>(rowptr, srcs, wts, h2, dinv, b2, out, N);
}

// Round 3
// 246.625 us; speedup vs baseline: 4.7651x; 1.2012x over previous
//
#include <hip/hip_runtime.h>

#define TPB 256
#define SCAN_CHUNK 1024   // elements per scan block (256 thr x 4)

// ---------------- CSR build ----------------

__global__ __launch_bounds__(TPB) void k_hist(const int* __restrict__ dst,
                                              int* __restrict__ cnt, int E) {
    int e = blockIdx.x * TPB + threadIdx.x;
    if (e < E) atomicAdd(&cnt[dst[e]], 1);
}

// scan pass A: per-block sums of SCAN_CHUNK counts
__global__ __launch_bounds__(TPB) void k_scan_a(const int* __restrict__ cnt,
                                                int* __restrict__ bsum, int N) {
    __shared__ int sh[TPB];
    int t = threadIdx.x;
    int base = blockIdx.x * SCAN_CHUNK + t * 4;
    int s = 0;
#pragma unroll
    for (int j = 0; j < 4; j++) { int idx = base + j; if (idx < N) s += cnt[idx]; }
    sh[t] = s; __syncthreads();
    for (int off = TPB / 2; off > 0; off >>= 1) {
        if (t < off) sh[t] += sh[t + off];
        __syncthreads();
    }
    if (t == 0) bsum[blockIdx.x] = sh[0];
}

// scan pass B: serial exclusive scan of block sums (~49 blocks)
__global__ void k_scan_b(const int* __restrict__ bsum, int* __restrict__ boff, int nb) {
    if (threadIdx.x == 0 && blockIdx.x == 0) {
        int run = 0;
        for (int i = 0; i < nb; i++) { boff[i] = run; run += bsum[i]; }
    }
}

// scan pass C: full exclusive scan -> rowptr + cursor; also dinv = rsqrt(deg+1)
__global__ __launch_bounds__(TPB) void k_scan_c(const int* __restrict__ cnt,
                                                const int* __restrict__ boff,
                                                int* __restrict__ rowptr,
                                                int* __restrict__ cursor,
                                                float* __restrict__ dinv, int N, int E) {
    __shared__ int sh[TPB];
    int t = threadIdx.x;
    int base = blockIdx.x * SCAN_CHUNK + t * 4;
    int v[4];
#pragma unroll
    for (int j = 0; j < 4; j++) { int idx = base + j; v[j] = (idx < N) ? cnt[idx] : 0; }
    int tsum = v[0] + v[1] + v[2] + v[3];
    sh[t] = tsum; __syncthreads();
    for (int off = 1; off < TPB; off <<= 1) {
        int x = (t >= off) ? sh[t - off] : 0;
        __syncthreads();
        sh[t] += x;
        __syncthreads();
    }
    int excl = sh[t] - tsum + boff[blockIdx.x];
#pragma unroll
    for (int j = 0; j < 4; j++) {
        int idx = base + j;
        if (idx < N) {
            rowptr[idx] = excl; cursor[idx] = excl;
            dinv[idx] = rsqrtf((float)(v[j] + 1));   // self-loop -> deg>=1
        }
        excl += v[j];
    }
    if (blockIdx.x == 0 && t == 0) rowptr[N] = E;
}

// fill: slot edges into CSR; payload packed {src, weight_bits} -> ONE 8B store/edge
__global__ __launch_bounds__(TPB) void k_fill(const int* __restrict__ src,
                                              const int* __restrict__ dst,
                                              const float* __restrict__ dinv,
                                              int* __restrict__ cursor,
                                              int2* __restrict__ edges, int E) {
    int e = blockIdx.x * TPB + threadIdx.x;
    if (e >= E) return;
    int s = src[e], d = dst[e];
    float w = dinv[s] * dinv[d];
    int pos = atomicAdd(&cursor[d], 1);
    edges[pos] = make_int2(s, __float_as_int(w));
}

// ---------------- GEMM1: H[N,64] = X[N,128] @ W[128,64] ----------------

__global__ __launch_bounds__(TPB) void k_gemm1(const float* __restrict__ X,
                                               const float* __restrict__ W,
                                               float* __restrict__ H, int N) {
    __shared__ float Xs[64 * 132];
    __shared__ float Ws[128 * 64];
    int t = threadIdx.x;
    int row0 = blockIdx.x * 64;

    const float4* W4 = (const float4*)W;
    float4* Ws4 = (float4*)Ws;
#pragma unroll
    for (int i = 0; i < 8; i++) Ws4[t + i * 256] = W4[t + i * 256];

    int rows = N - row0; if (rows > 64) rows = 64;
    const float4* X4 = (const float4*)(X + (size_t)row0 * 128);
    float4* Xs4 = (float4*)Xs;
    for (int i = t; i < rows * 32; i += TPB) {
        int rr = i >> 5, kk = i & 31;
        Xs4[rr * 33 + kk] = X4[i];
    }
    __syncthreads();

    int r = t >> 2;
    int c0 = (t & 3) * 16;
    float acc[16];
#pragma unroll
    for (int j = 0; j < 16; j++) acc[j] = 0.0f;
    const float* xrow = Xs + r * 132;
#pragma unroll 2
    for (int k = 0; k < 128; k++) {
        float xv = xrow[k];
        const float* wr = Ws + k * 64 + c0;
#pragma unroll
        for (int j = 0; j < 16; j++) acc[j] += xv * wr[j];
    }
    if (row0 + r < N) {
        float* o = H + (size_t)(row0 + r) * 64 + c0;
#pragma unroll
        for (int j = 0; j < 16; j++) o[j] = acc[j];
    }
}

// ---------------- GEMM2: H[N,32] = Xin[N,64] @ W[64,32] ----------------

__global__ __launch_bounds__(TPB) void k_gemm2(const float* __restrict__ Xin,
                                               const float* __restrict__ W,
                                               float* __restrict__ H, int N) {
    __shared__ float Xs[64 * 68];
    __shared__ float Ws[64 * 32];
    int t = threadIdx.x;
    int row0 = blockIdx.x * 64;

    const float4* W4 = (const float4*)W;
    float4* Ws4 = (float4*)Ws;
#pragma unroll
    for (int i = 0; i < 2; i++) Ws4[t + i * 256] = W4[t + i * 256];

    int rows = N - row0; if (rows > 64) rows = 64;
    const float4* X4 = (const float4*)(Xin + (size_t)row0 * 64);
    float4* Xs4 = (float4*)Xs;
    for (int i = t; i < rows * 16; i += TPB) {
        int rr = i >> 4, kk = i & 15;
        Xs4[rr * 17 + kk] = X4[i];
    }
    __syncthreads();

    int r = t >> 2;
    int c0 = (t & 3) * 8;
    float acc[8];
#pragma unroll
    for (int j = 0; j < 8; j++) acc[j] = 0.0f;
    const float* xrow = Xs + r * 68;
#pragma unroll 4
    for (int k = 0; k < 64; k++) {
        float xv = xrow[k];
        const float* wr = Ws + k * 32 + c0;
#pragma unroll
        for (int j = 0; j < 8; j++) acc[j] += xv * wr[j];
    }
    if (row0 + r < N) {
        float* o = H + (size_t)(row0 + r) * 32 + c0;
#pragma unroll
        for (int j = 0; j < 8; j++) o[j] = acc[j];
    }
}

// ---------------- gather (float4 lanes): out[n] = relu( sum_e H[src_e]*w_e
//                                         + H[n]*dinv[n]^2 + b ) ----------------
// L = F/4 lanes per node; edge payload is an 8B broadcast; H row read is one
// coalesced L*16B transaction per edge.

template <int F>
__global__ __launch_bounds__(TPB) void k_gather(const int* __restrict__ rowptr,
                                                const int2* __restrict__ edges,
                                                const float* __restrict__ H,
                                                const float* __restrict__ dinv,
                                                const float* __restrict__ bias,
                                                float* __restrict__ out, int N) {
    const int L = F / 4;
    int t = threadIdx.x;
    int node = blockIdx.x * (TPB / L) + t / L;
    int lane = t % L;
    if (node >= N) return;

    const float4* H4 = (const float4*)H;
    float w0 = dinv[node]; w0 *= w0;
    float4 v = H4[(size_t)node * L + lane];
    float4 bb = ((const float4*)bias)[lane];
    float4 acc = { fmaf(v.x, w0, bb.x), fmaf(v.y, w0, bb.y),
                   fmaf(v.z, w0, bb.z), fmaf(v.w, w0, bb.w) };

    int i = rowptr[node], end = rowptr[node + 1];
    for (; i + 1 < end; i += 2) {
        int2 e0 = edges[i], e1 = edges[i + 1];
        float4 h0 = H4[(size_t)e0.x * L + lane];
        float4 h1 = H4[(size_t)e1.x * L + lane];
        float wa = __int_as_float(e0.y), wb = __int_as_float(e1.y);
        acc.x = fmaf(h0.x, wa, acc.x); acc.y = fmaf(h0.y, wa, acc.y);
        acc.z = fmaf(h0.z, wa, acc.z); acc.w = fmaf(h0.w, wa, acc.w);
        acc.x = fmaf(h1.x, wb, acc.x); acc.y = fmaf(h1.y, wb, acc.y);
        acc.z = fmaf(h1.z, wb, acc.z); acc.w = fmaf(h1.w, wb, acc.w);
    }
    if (i < end) {
        int2 e0 = edges[i];
        float4 h0 = H4[(size_t)e0.x * L + lane];
        float wa = __int_as_float(e0.y);
        acc.x = fmaf(h0.x, wa, acc.x); acc.y = fmaf(h0.y, wa, acc.y);
        acc.z = fmaf(h0.z, wa, acc.z); acc.w = fmaf(h0.w, wa, acc.w);
    }
    float4 o = { fmaxf(acc.x, 0.0f), fmaxf(acc.y, 0.0f),
                 fmaxf(acc.z, 0.0f), fmaxf(acc.w, 0.0f) };
    ((float4*)out)[(size_t)node * L + lane] = o;
}

static inline int cdiv(int a, int b) { return (a + b - 1) / b; }
static inline char* alignup(char* p) { return (char*)(((uintptr_t)p + 255) & ~(uintptr_t)255); }

extern "C" void kernel_launch(void* const* d_in, const int* in_sizes, int n_in,
                              void* d_out, int out_size, void* d_ws, size_t ws_size,
                              hipStream_t stream) {
    const float* x  = (const float*)d_in[0];
    const int*   ei = (const int*)d_in[1];
    const float* W1 = (const float*)d_in[2];
    const float* b1 = (const float*)d_in[3];
    const float* W2 = (const float*)d_in[4];
    const float* b2 = (const float*)d_in[5];
    float* out = (float*)d_out;

    int N = in_sizes[0] / 128;
    int E = in_sizes[1] / 2;
    const int* src = ei;
    const int* dst = ei + E;

    char* p = (char*)d_ws;
    float* dinv  = (float*)p;   p = alignup(p + sizeof(float) * N);
    int* cnt     = (int*)p;     p = alignup(p + sizeof(int) * N);
    int* rowptr  = (int*)p;     p = alignup(p + sizeof(int) * (N + 1));
    int* cursor  = (int*)p;     p = alignup(p + sizeof(int) * N);
    int* bsum    = (int*)p;     p = alignup(p + sizeof(int) * 256);
    int* boff    = (int*)p;     p = alignup(p + sizeof(int) * 256);
    int2* edges  = (int2*)p;    p = alignup(p + sizeof(int2) * E);
    float* h1    = (float*)p;   p = alignup(p + sizeof(float) * (size_t)N * 64);
    float* out1  = (float*)p;   p = alignup(p + sizeof(float) * (size_t)N * 64);
    float* h2    = (float*)p;   p = alignup(p + sizeof(float) * (size_t)N * 32);

    dim3 b(TPB);
    int nscan = cdiv(N, SCAN_CHUNK);

    // ---- CSR build (also produces dinv) ----
    hipMemsetAsync(cnt, 0, sizeof(int) * N, stream);
    k_hist  <<<cdiv(E, TPB), b, 0, stream>>>(dst, cnt, E);
    k_scan_a<<<nscan, b, 0, stream>>>(cnt, bsum, N);
    k_scan_b<<<1, 64, 0, stream>>>(bsum, boff, nscan);
    k_scan_c<<<nscan, b, 0, stream>>>(cnt, boff, rowptr, cursor, dinv, N, E);
    k_fill  <<<cdiv(E, TPB), b, 0, stream>>>(src, dst, dinv, cursor, edges, E);

    // ---- layer 1 ----
    k_gemm1      <<<cdiv(N, 64), b, 0, stream>>>(x, W1, h1, N);
    k_gather<64> <<<cdiv(N, TPB / 16), b, 0, stream>>>(rowptr, edges, h1, dinv, b1, out1, N);

    // ---- layer 2 ----
    k_gemm2      <<<cdiv(N, 64), b, 0, stream>>>(out1, W2, h2, N);
    k_gather<32> <<<cdiv(N, TPB / 8), b, 0, stream>>>(rowptr, edges, h2, dinv, b2, out, N);
}

// Round 4
// 211.290 us; speedup vs baseline: 5.5620x; 1.1672x over previous
//
#include <hip/hip_runtime.h>

#define TPB 256
#define SCAN_CHUNK 1024   // elements per scan block (256 thr x 4)

// ---------------- CSR build ----------------

// hist + slot capture: slot[e] = running index of e within its dst node.
__global__ __launch_bounds__(TPB) void k_hist(const int* __restrict__ dst,
                                              int* __restrict__ cnt,
                                              int* __restrict__ slot, int E) {
    int e = blockIdx.x * TPB + threadIdx.x;
    if (e < E) slot[e] = atomicAdd(&cnt[dst[e]], 1);
}

// scan pass A: per-block sums of SCAN_CHUNK counts
__global__ __launch_bounds__(TPB) void k_scan_a(const int* __restrict__ cnt,
                                                int* __restrict__ bsum, int N) {
    __shared__ int sh[TPB];
    int t = threadIdx.x;
    int base = blockIdx.x * SCAN_CHUNK + t * 4;
    int s = 0;
#pragma unroll
    for (int j = 0; j < 4; j++) { int idx = base + j; if (idx < N) s += cnt[idx]; }
    sh[t] = s; __syncthreads();
    for (int off = TPB / 2; off > 0; off >>= 1) {
        if (t < off) sh[t] += sh[t + off];
        __syncthreads();
    }
    if (t == 0) bsum[blockIdx.x] = sh[0];
}

// scan pass B: serial exclusive scan of block sums (~49 blocks)
__global__ void k_scan_b(const int* __restrict__ bsum, int* __restrict__ boff, int nb) {
    if (threadIdx.x == 0 && blockIdx.x == 0) {
        int run = 0;
        for (int i = 0; i < nb; i++) { boff[i] = run; run += bsum[i]; }
    }
}

// scan pass C: full exclusive scan -> rowptr; dinv = rsqrt(deg+1)
__global__ __launch_bounds__(TPB) void k_scan_c(const int* __restrict__ cnt,
                                                const int* __restrict__ boff,
                                                int* __restrict__ rowptr,
                                                float* __restrict__ dinv, int N, int E) {
    __shared__ int sh[TPB];
    int t = threadIdx.x;
    int base = blockIdx.x * SCAN_CHUNK + t * 4;
    int v[4];
#pragma unroll
    for (int j = 0; j < 4; j++) { int idx = base + j; v[j] = (idx < N) ? cnt[idx] : 0; }
    int tsum = v[0] + v[1] + v[2] + v[3];
    sh[t] = tsum; __syncthreads();
    for (int off = 1; off < TPB; off <<= 1) {
        int x = (t >= off) ? sh[t - off] : 0;
        __syncthreads();
        sh[t] += x;
        __syncthreads();
    }
    int excl = sh[t] - tsum + boff[blockIdx.x];
#pragma unroll
    for (int j = 0; j < 4; j++) {
        int idx = base + j;
        if (idx < N) {
            rowptr[idx] = excl;
            dinv[idx] = rsqrtf((float)(v[j] + 1));   // self-loop -> deg>=1
        }
        excl += v[j];
    }
    if (blockIdx.x == 0 && t == 0) rowptr[N] = E;
}

// ---------------- FAT kernel: CSR fill  ||  GEMM1 ----------------
// One dispatch, two block kinds interleaved 1-in-5 so gemm (compute-heavy)
// co-resides with fill (latency-bound random stores, VALU idle) on every CU.
// gemm1 uses Ws-only LDS (32 KB) -> 5 blocks/CU -> fill keeps ~20 waves/CU.

__global__ __launch_bounds__(TPB) void k_fill_gemm1(
        // fill args
        const int* __restrict__ src, const int* __restrict__ dst,
        const int* __restrict__ slot, const int* __restrict__ rowptr,
        const float* __restrict__ dinv, int2* __restrict__ edges, int E,
        // gemm args: H[N,64] = X[N,128] @ W[128,64]
        const float* __restrict__ X, const float* __restrict__ W,
        float* __restrict__ H, int N, int G1) {
    __shared__ float Ws[128 * 64];
    int bid = blockIdx.x;
    int t = threadIdx.x;

    if ((bid % 5) == 4) {
        // ---- gemm block (bid/5 < G1 guaranteed by grid sizing) ----
        int gb = bid / 5;
        int row0 = gb * 64;

        const float4* W4 = (const float4*)W;
        float4* Ws4 = (float4*)Ws;
#pragma unroll
        for (int i = 0; i < 8; i++) Ws4[t + i * 256] = W4[t + i * 256];
        __syncthreads();

        int r = t >> 2;
        int c0 = (t & 3) * 16;
        if (row0 + r >= N) return;

        const float4* xr = (const float4*)(X + (size_t)(row0 + r) * 128);
        float acc[16];
#pragma unroll
        for (int j = 0; j < 16; j++) acc[j] = 0.0f;

        for (int kk = 0; kk < 32; kk++) {
            float4 xv = xr[kk];
            const float* w0 = Ws + (4 * kk) * 64 + c0;
#pragma unroll
            for (int j = 0; j < 16; j++) acc[j] = fmaf(xv.x, w0[j], acc[j]);
#pragma unroll
            for (int j = 0; j < 16; j++) acc[j] = fmaf(xv.y, w0[64 + j], acc[j]);
#pragma unroll
            for (int j = 0; j < 16; j++) acc[j] = fmaf(xv.z, w0[128 + j], acc[j]);
#pragma unroll
            for (int j = 0; j < 16; j++) acc[j] = fmaf(xv.w, w0[192 + j], acc[j]);
        }
        float* o = H + (size_t)(row0 + r) * 64 + c0;
#pragma unroll
        for (int j = 0; j < 16; j++) o[j] = acc[j];
    } else {
        // ---- fill block ----
        int fidx = bid - bid / 5;           // count of gemm blocks before bid
        int e = fidx * TPB + t;
        if (e >= E) return;
        int s = src[e], d = dst[e];
        float w = dinv[s] * dinv[d];
        int pos = rowptr[d] + slot[e];
        edges[pos] = make_int2(s, __float_as_int(w));
    }
}

// ---------------- GEMM2: H[N,32] = Xin[N,64] @ W[64,32] ----------------

__global__ __launch_bounds__(TPB) void k_gemm2(const float* __restrict__ Xin,
                                               const float* __restrict__ W,
                                               float* __restrict__ H, int N) {
    __shared__ float Xs[64 * 68];
    __shared__ float Ws[64 * 32];
    int t = threadIdx.x;
    int row0 = blockIdx.x * 64;

    const float4* W4 = (const float4*)W;
    float4* Ws4 = (float4*)Ws;
#pragma unroll
    for (int i = 0; i < 2; i++) Ws4[t + i * 256] = W4[t + i * 256];

    int rows = N - row0; if (rows > 64) rows = 64;
    const float4* X4 = (const float4*)(Xin + (size_t)row0 * 64);
    float4* Xs4 = (float4*)Xs;
    for (int i = t; i < rows * 16; i += TPB) {
        int rr = i >> 4, kk = i & 15;
        Xs4[rr * 17 + kk] = X4[i];
    }
    __syncthreads();

    int r = t >> 2;
    int c0 = (t & 3) * 8;
    float acc[8];
#pragma unroll
    for (int j = 0; j < 8; j++) acc[j] = 0.0f;
    const float* xrow = Xs + r * 68;
#pragma unroll 4
    for (int k = 0; k < 64; k++) {
        float xv = xrow[k];
        const float* wr = Ws + k * 32 + c0;
#pragma unroll
        for (int j = 0; j < 8; j++) acc[j] += xv * wr[j];
    }
    if (row0 + r < N) {
        float* o = H + (size_t)(row0 + r) * 32 + c0;
#pragma unroll
        for (int j = 0; j < 8; j++) o[j] = acc[j];
    }
}

// ---------------- gather (float4 lanes) ----------------

template <int F>
__global__ __launch_bounds__(TPB) void k_gather(const int* __restrict__ rowptr,
                                                const int2* __restrict__ edges,
                                                const float* __restrict__ H,
                                                const float* __restrict__ dinv,
                                                const float* __restrict__ bias,
                                                float* __restrict__ out, int N) {
    const int L = F / 4;
    int t = threadIdx.x;
    int node = blockIdx.x * (TPB / L) + t / L;
    int lane = t % L;
    if (node >= N) return;

    const float4* H4 = (const float4*)H;
    float w0 = dinv[node]; w0 *= w0;
    float4 v = H4[(size_t)node * L + lane];
    float4 bb = ((const float4*)bias)[lane];
    float4 acc = { fmaf(v.x, w0, bb.x), fmaf(v.y, w0, bb.y),
                   fmaf(v.z, w0, bb.z), fmaf(v.w, w0, bb.w) };

    int i = rowptr[node], end = rowptr[node + 1];
    for (; i + 1 < end; i += 2) {
        int2 e0 = edges[i], e1 = edges[i + 1];
        float4 h0 = H4[(size_t)e0.x * L + lane];
        float4 h1 = H4[(size_t)e1.x * L + lane];
        float wa = __int_as_float(e0.y), wb = __int_as_float(e1.y);
        acc.x = fmaf(h0.x, wa, acc.x); acc.y = fmaf(h0.y, wa, acc.y);
        acc.z = fmaf(h0.z, wa, acc.z); acc.w = fmaf(h0.w, wa, acc.w);
        acc.x = fmaf(h1.x, wb, acc.x); acc.y = fmaf(h1.y, wb, acc.y);
        acc.z = fmaf(h1.z, wb, acc.z); acc.w = fmaf(h1.w, wb, acc.w);
    }
    if (i < end) {
        int2 e0 = edges[i];
        float4 h0 = H4[(size_t)e0.x * L + lane];
        float wa = __int_as_float(e0.y);
        acc.x = fmaf(h0.x, wa, acc.x); acc.y = fmaf(h0.y, wa, acc.y);
        acc.z = fmaf(h0.z, wa, acc.z); acc.w = fmaf(h0.w, wa, acc.w);
    }
    float4 o = { fmaxf(acc.x, 0.0f), fmaxf(acc.y, 0.0f),
                 fmaxf(acc.z, 0.0f), fmaxf(acc.w, 0.0f) };
    ((float4*)out)[(size_t)node * L + lane] = o;
}

static inline int cdiv(int a, int b) { return (a + b - 1) / b; }
static inline char* alignup(char* p) { return (char*)(((uintptr_t)p + 255) & ~(uintptr_t)255); }

extern "C" void kernel_launch(void* const* d_in, const int* in_sizes, int n_in,
                              void* d_out, int out_size, void* d_ws, size_t ws_size,
                              hipStream_t stream) {
    const float* x  = (const float*)d_in[0];
    const int*   ei = (const int*)d_in[1];
    const float* W1 = (const float*)d_in[2];
    const float* b1 = (const float*)d_in[3];
    const float* W2 = (const float*)d_in[4];
    const float* b2 = (const float*)d_in[5];
    float* out = (float*)d_out;

    int N = in_sizes[0] / 128;
    int E = in_sizes[1] / 2;
    const int* src = ei;
    const int* dst = ei + E;

    char* p = (char*)d_ws;
    float* dinv  = (float*)p;   p = alignup(p + sizeof(float) * N);
    int* cnt     = (int*)p;     p = alignup(p + sizeof(int) * N);
    int* rowptr  = (int*)p;     p = alignup(p + sizeof(int) * (N + 1));
    int* slot    = (int*)p;     p = alignup(p + sizeof(int) * E);
    int* bsum    = (int*)p;     p = alignup(p + sizeof(int) * 256);
    int* boff    = (int*)p;     p = alignup(p + sizeof(int) * 256);
    int2* edges  = (int2*)p;    p = alignup(p + sizeof(int2) * E);
    float* h1    = (float*)p;   p = alignup(p + sizeof(float) * (size_t)N * 64);
    float* out1  = (float*)p;   p = alignup(p + sizeof(float) * (size_t)N * 64);
    float* h2    = (float*)p;   p = alignup(p + sizeof(float) * (size_t)N * 32);

    dim3 b(TPB);
    int nscan = cdiv(N, SCAN_CHUNK);
    int G1 = cdiv(N, 64);                 // gemm1 blocks
    int GF = cdiv(E, TPB);                // fill blocks
    int fat = G1 * 5;                     // gemm at bid%5==4; must cover GF+G1
    if (fat < GF + G1) fat = GF + G1 + 4; // (not hit here; safety)

    // ---- CSR build ----
    hipMemsetAsync(cnt, 0, sizeof(int) * N, stream);
    k_hist  <<<cdiv(E, TPB), b, 0, stream>>>(dst, cnt, slot, E);
    k_scan_a<<<nscan, b, 0, stream>>>(cnt, bsum, N);
    k_scan_b<<<1, 64, 0, stream>>>(bsum, boff, nscan);
    k_scan_c<<<nscan, b, 0, stream>>>(cnt, boff, rowptr, dinv, N, E);

    // ---- fill || gemm1 (independent work overlapped in one dispatch) ----
    k_fill_gemm1<<<fat, b, 0, stream>>>(src, dst, slot, rowptr, dinv, edges, E,
                                        x, W1, h1, N, G1);

    // ---- layer 1 aggregate ----
    k_gather<64> <<<cdiv(N, TPB / 16), b, 0, stream>>>(rowptr, edges, h1, dinv, b1, out1, N);

    // ---- layer 2 ----
    k_gemm2      <<<cdiv(N, 64), b, 0, stream>>>(out1, W2, h2, N);
    k_gather<32> <<<cdiv(N, TPB / 8), b, 0, stream>>>(rowptr, edges, h2, dinv, b2, out, N);
}

// Round 5
// 206.326 us; speedup vs baseline: 5.6959x; 1.0241x over previous
//
#include <hip/hip_runtime.h>

#define TPB 256
#define SCAN_CHUNK 1024   // elements per scan block (256 thr x 4)

// ---------------- CSR build ----------------

// hist + slot capture: slot[e] = running index of e within its dst node.
__global__ __launch_bounds__(TPB) void k_hist(const int* __restrict__ dst,
                                              int* __restrict__ cnt,
                                              int* __restrict__ slot, int E) {
    int e = blockIdx.x * TPB + threadIdx.x;
    if (e < E) slot[e] = atomicAdd(&cnt[dst[e]], 1);
}

__global__ __launch_bounds__(TPB) void k_scan_a(const int* __restrict__ cnt,
                                                int* __restrict__ bsum, int N) {
    __shared__ int sh[TPB];
    int t = threadIdx.x;
    int base = blockIdx.x * SCAN_CHUNK + t * 4;
    int s = 0;
#pragma unroll
    for (int j = 0; j < 4; j++) { int idx = base + j; if (idx < N) s += cnt[idx]; }
    sh[t] = s; __syncthreads();
    for (int off = TPB / 2; off > 0; off >>= 1) {
        if (t < off) sh[t] += sh[t + off];
        __syncthreads();
    }
    if (t == 0) bsum[blockIdx.x] = sh[0];
}

__global__ void k_scan_b(const int* __restrict__ bsum, int* __restrict__ boff, int nb) {
    if (threadIdx.x == 0 && blockIdx.x == 0) {
        int run = 0;
        for (int i = 0; i < nb; i++) { boff[i] = run; run += bsum[i]; }
    }
}

__global__ __launch_bounds__(TPB) void k_scan_c(const int* __restrict__ cnt,
                                                const int* __restrict__ boff,
                                                int* __restrict__ rowptr,
                                                float* __restrict__ dinv, int N, int E) {
    __shared__ int sh[TPB];
    int t = threadIdx.x;
    int base = blockIdx.x * SCAN_CHUNK + t * 4;
    int v[4];
#pragma unroll
    for (int j = 0; j < 4; j++) { int idx = base + j; v[j] = (idx < N) ? cnt[idx] : 0; }
    int tsum = v[0] + v[1] + v[2] + v[3];
    sh[t] = tsum; __syncthreads();
    for (int off = 1; off < TPB; off <<= 1) {
        int x = (t >= off) ? sh[t - off] : 0;
        __syncthreads();
        sh[t] += x;
        __syncthreads();
    }
    int excl = sh[t] - tsum + boff[blockIdx.x];
#pragma unroll
    for (int j = 0; j < 4; j++) {
        int idx = base + j;
        if (idx < N) {
            rowptr[idx] = excl;
            dinv[idx] = rsqrtf((float)(v[j] + 1));   // self-loop -> deg>=1
        }
        excl += v[j];
    }
    if (blockIdx.x == 0 && t == 0) rowptr[N] = E;
}

// ---------------- FAT kernel: CSR fill  ||  GEMM1 ----------------

__global__ __launch_bounds__(TPB) void k_fill_gemm1(
        const int* __restrict__ src, const int* __restrict__ dst,
        const int* __restrict__ slot, const int* __restrict__ rowptr,
        const float* __restrict__ dinv, int2* __restrict__ edges, int E,
        const float* __restrict__ X, const float* __restrict__ W,
        float* __restrict__ H, int N, int G1) {
    __shared__ float Ws[128 * 64];
    int bid = blockIdx.x;
    int t = threadIdx.x;

    if ((bid % 5) == 4) {
        int gb = bid / 5;
        int row0 = gb * 64;

        const float4* W4 = (const float4*)W;
        float4* Ws4 = (float4*)Ws;
#pragma unroll
        for (int i = 0; i < 8; i++) Ws4[t + i * 256] = W4[t + i * 256];
        __syncthreads();

        int r = t >> 2;
        int c0 = (t & 3) * 16;
        if (row0 + r >= N) return;

        const float4* xr = (const float4*)(X + (size_t)(row0 + r) * 128);
        float acc[16];
#pragma unroll
        for (int j = 0; j < 16; j++) acc[j] = 0.0f;

        for (int kk = 0; kk < 32; kk++) {
            float4 xv = xr[kk];
            const float* w0 = Ws + (4 * kk) * 64 + c0;
#pragma unroll
            for (int j = 0; j < 16; j++) acc[j] = fmaf(xv.x, w0[j], acc[j]);
#pragma unroll
            for (int j = 0; j < 16; j++) acc[j] = fmaf(xv.y, w0[64 + j], acc[j]);
#pragma unroll
            for (int j = 0; j < 16; j++) acc[j] = fmaf(xv.z, w0[128 + j], acc[j]);
#pragma unroll
            for (int j = 0; j < 16; j++) acc[j] = fmaf(xv.w, w0[192 + j], acc[j]);
        }
        float* o = H + (size_t)(row0 + r) * 64 + c0;
#pragma unroll
        for (int j = 0; j < 16; j++) o[j] = acc[j];
    } else {
        int fidx = bid - bid / 5;
        int e = fidx * TPB + t;
        if (e >= E) return;
        int s = src[e], d = dst[e];
        float w = dinv[s] * dinv[d];
        int pos = rowptr[d] + slot[e];
        edges[pos] = make_int2(s, __float_as_int(w));
    }
}

// ---------------- fused: layer-1 aggregate + relu + GEMM2 ----------------
// 16 lanes/node (float4 each over F=64), 16 nodes/block. Aggregated+relu'd
// row goes through LDS (stride 68: float4-aligned, conflict-free dot phase),
// then the block computes h2 = row @ W2 (W2 in LDS).

__global__ __launch_bounds__(TPB) void k_gather_gemm(
        const int* __restrict__ rowptr, const int2* __restrict__ edges,
        const float* __restrict__ H, const float* __restrict__ dinv,
        const float* __restrict__ bias, const float* __restrict__ W2,
        float* __restrict__ H2, int N) {
    __shared__ float W2s[64 * 32];   // 8 KB
    __shared__ float rows[16 * 68];  // 4.25 KB, stride 68
    int t = threadIdx.x;

    { // stage W2
        const float4* W4 = (const float4*)W2;
        float4* Ws4 = (float4*)W2s;
#pragma unroll
        for (int i = 0; i < 2; i++) Ws4[t + i * 256] = W4[t + i * 256];
    }

    int node = blockIdx.x * 16 + (t >> 4);
    int lane = t & 15;

    if (node < N) {
        const float4* H4 = (const float4*)H;
        float w0 = dinv[node]; w0 *= w0;
        float4 v = H4[(size_t)node * 16 + lane];
        float4 bb = ((const float4*)bias)[lane];
        float4 acc = { fmaf(v.x, w0, bb.x), fmaf(v.y, w0, bb.y),
                       fmaf(v.z, w0, bb.z), fmaf(v.w, w0, bb.w) };

        int i = rowptr[node], end = rowptr[node + 1];
        for (; i + 3 < end; i += 4) {
            int2 e0 = edges[i], e1 = edges[i + 1], e2 = edges[i + 2], e3 = edges[i + 3];
            float4 h0 = H4[(size_t)e0.x * 16 + lane];
            float4 h1 = H4[(size_t)e1.x * 16 + lane];
            float4 h2 = H4[(size_t)e2.x * 16 + lane];
            float4 h3 = H4[(size_t)e3.x * 16 + lane];
            float wa = __int_as_float(e0.y), wb = __int_as_float(e1.y);
            float wc = __int_as_float(e2.y), wd = __int_as_float(e3.y);
            acc.x = fmaf(h0.x, wa, acc.x); acc.y = fmaf(h0.y, wa, acc.y);
            acc.z = fmaf(h0.z, wa, acc.z); acc.w = fmaf(h0.w, wa, acc.w);
            acc.x = fmaf(h1.x, wb, acc.x); acc.y = fmaf(h1.y, wb, acc.y);
            acc.z = fmaf(h1.z, wb, acc.z); acc.w = fmaf(h1.w, wb, acc.w);
            acc.x = fmaf(h2.x, wc, acc.x); acc.y = fmaf(h2.y, wc, acc.y);
            acc.z = fmaf(h2.z, wc, acc.z); acc.w = fmaf(h2.w, wc, acc.w);
            acc.x = fmaf(h3.x, wd, acc.x); acc.y = fmaf(h3.y, wd, acc.y);
            acc.z = fmaf(h3.z, wd, acc.z); acc.w = fmaf(h3.w, wd, acc.w);
        }
        for (; i < end; i++) {
            int2 e0 = edges[i];
            float4 h0 = H4[(size_t)e0.x * 16 + lane];
            float wa = __int_as_float(e0.y);
            acc.x = fmaf(h0.x, wa, acc.x); acc.y = fmaf(h0.y, wa, acc.y);
            acc.z = fmaf(h0.z, wa, acc.z); acc.w = fmaf(h0.w, wa, acc.w);
        }
        float4 r = { fmaxf(acc.x, 0.0f), fmaxf(acc.y, 0.0f),
                     fmaxf(acc.z, 0.0f), fmaxf(acc.w, 0.0f) };
        *(float4*)&rows[(t >> 4) * 68 + lane * 4] = r;
    }
    __syncthreads();

    // gemm phase: thread t -> node n = t/16, cols c = t%16 and t%16+16
    int n = t >> 4;
    int c = t & 15;
    int gnode = blockIdx.x * 16 + n;
    if (gnode >= N) return;
    const float* row = rows + n * 68;
    float a0 = 0.0f, a1 = 0.0f;
#pragma unroll 8
    for (int k = 0; k < 64; k++) {
        float rv = row[k];
        a0 = fmaf(rv, W2s[k * 32 + c], a0);
        a1 = fmaf(rv, W2s[k * 32 + c + 16], a1);
    }
    float* o = H2 + (size_t)gnode * 32;
    o[c] = a0;
    o[c + 16] = a1;
}

// ---------------- gather layer 2 (F=32): out = relu(agg + self + b) ----------------

__global__ __launch_bounds__(TPB) void k_gather32(const int* __restrict__ rowptr,
                                                  const int2* __restrict__ edges,
                                                  const float* __restrict__ H,
                                                  const float* __restrict__ dinv,
                                                  const float* __restrict__ bias,
                                                  float* __restrict__ out, int N) {
    const int L = 8;
    int t = threadIdx.x;
    int node = blockIdx.x * (TPB / L) + t / L;
    int lane = t % L;
    if (node >= N) return;

    const float4* H4 = (const float4*)H;
    float w0 = dinv[node]; w0 *= w0;
    float4 v = H4[(size_t)node * L + lane];
    float4 bb = ((const float4*)bias)[lane];
    float4 acc = { fmaf(v.x, w0, bb.x), fmaf(v.y, w0, bb.y),
                   fmaf(v.z, w0, bb.z), fmaf(v.w, w0, bb.w) };

    int i = rowptr[node], end = rowptr[node + 1];
    for (; i + 3 < end; i += 4) {
        int2 e0 = edges[i], e1 = edges[i + 1], e2 = edges[i + 2], e3 = edges[i + 3];
        float4 h0 = H4[(size_t)e0.x * L + lane];
        float4 h1 = H4[(size_t)e1.x * L + lane];
        float4 h2 = H4[(size_t)e2.x * L + lane];
        float4 h3 = H4[(size_t)e3.x * L + lane];
        float wa = __int_as_float(e0.y), wb = __int_as_float(e1.y);
        float wc = __int_as_float(e2.y), wd = __int_as_float(e3.y);
        acc.x = fmaf(h0.x, wa, acc.x); acc.y = fmaf(h0.y, wa, acc.y);
        acc.z = fmaf(h0.z, wa, acc.z); acc.w = fmaf(h0.w, wa, acc.w);
        acc.x = fmaf(h1.x, wb, acc.x); acc.y = fmaf(h1.y, wb, acc.y);
        acc.z = fmaf(h1.z, wb, acc.z); acc.w = fmaf(h1.w, wb, acc.w);
        acc.x = fmaf(h2.x, wc, acc.x); acc.y = fmaf(h2.y, wc, acc.y);
        acc.z = fmaf(h2.z, wc, acc.z); acc.w = fmaf(h2.w, wc, acc.w);
        acc.x = fmaf(h3.x, wd, acc.x); acc.y = fmaf(h3.y, wd, acc.y);
        acc.z = fmaf(h3.z, wd, acc.z); acc.w = fmaf(h3.w, wd, acc.w);
    }
    for (; i < end; i++) {
        int2 e0 = edges[i];
        float4 h0 = H4[(size_t)e0.x * L + lane];
        float wa = __int_as_float(e0.y);
        acc.x = fmaf(h0.x, wa, acc.x); acc.y = fmaf(h0.y, wa, acc.y);
        acc.z = fmaf(h0.z, wa, acc.z); acc.w = fmaf(h0.w, wa, acc.w);
    }
    float4 o = { fmaxf(acc.x, 0.0f), fmaxf(acc.y, 0.0f),
                 fmaxf(acc.z, 0.0f), fmaxf(acc.w, 0.0f) };
    ((float4*)out)[(size_t)node * L + lane] = o;
}

static inline int cdiv(int a, int b) { return (a + b - 1) / b; }
static inline char* alignup(char* p) { return (char*)(((uintptr_t)p + 255) & ~(uintptr_t)255); }

extern "C" void kernel_launch(void* const* d_in, const int* in_sizes, int n_in,
                              void* d_out, int out_size, void* d_ws, size_t ws_size,
                              hipStream_t stream) {
    const float* x  = (const float*)d_in[0];
    const int*   ei = (const int*)d_in[1];
    const float* W1 = (const float*)d_in[2];
    const float* b1 = (const float*)d_in[3];
    const float* W2 = (const float*)d_in[4];
    const float* b2 = (const float*)d_in[5];
    float* out = (float*)d_out;

    int N = in_sizes[0] / 128;
    int E = in_sizes[1] / 2;
    const int* src = ei;
    const int* dst = ei + E;

    char* p = (char*)d_ws;
    float* dinv  = (float*)p;   p = alignup(p + sizeof(float) * N);
    int* cnt     = (int*)p;     p = alignup(p + sizeof(int) * N);
    int* rowptr  = (int*)p;     p = alignup(p + sizeof(int) * (N + 1));
    int* slot    = (int*)p;     p = alignup(p + sizeof(int) * E);
    int* bsum    = (int*)p;     p = alignup(p + sizeof(int) * 256);
    int* boff    = (int*)p;     p = alignup(p + sizeof(int) * 256);
    int2* edges  = (int2*)p;    p = alignup(p + sizeof(int2) * E);
    float* h1    = (float*)p;   p = alignup(p + sizeof(float) * (size_t)N * 64);
    float* h2    = (float*)p;   p = alignup(p + sizeof(float) * (size_t)N * 32);

    dim3 b(TPB);
    int nscan = cdiv(N, SCAN_CHUNK);
    int G1 = cdiv(N, 64);
    int GF = cdiv(E, TPB);
    int fat = G1 * 5;
    if (fat < GF + G1) fat = GF + G1 + 4;

    // ---- CSR build ----
    hipMemsetAsync(cnt, 0, sizeof(int) * N, stream);
    k_hist  <<<cdiv(E, TPB), b, 0, stream>>>(dst, cnt, slot, E);
    k_scan_a<<<nscan, b, 0, stream>>>(cnt, bsum, N);
    k_scan_b<<<1, 64, 0, stream>>>(bsum, boff, nscan);
    k_scan_c<<<nscan, b, 0, stream>>>(cnt, boff, rowptr, dinv, N, E);

    // ---- fill || gemm1 ----
    k_fill_gemm1<<<fat, b, 0, stream>>>(src, dst, slot, rowptr, dinv, edges, E,
                                        x, W1, h1, N, G1);

    // ---- layer-1 aggregate + relu + gemm2 (fused) ----
    k_gather_gemm<<<cdiv(N, 16), b, 0, stream>>>(rowptr, edges, h1, dinv, b1, W2, h2, N);

    // ---- layer-2 aggregate ----
    k_gather32<<<cdiv(N, TPB / 8), b, 0, stream>>>(rowptr, edges, h2, dinv, b2, out, N);
}